// Round 4
// baseline (118.333 us; speedup 1.0000x reference)
//
#include <hip/hip_runtime.h>

// GRU encoder, MI355X — R2 kernel (2nd resubmit; two infra failures, zero measurements).
//  kernel 1: packed gate table Gpk[v][cw][c16][8] (bf16): slot gate+3*ht =
//            b_ih + embed@W_ih (+ b_hh folded for r,z). One dwordx4 per lane-row gather.
//  kernel 2: persistent GRU, 512 blocks x 256 thr (BB=16 rows, 4 waves), 2 blocks/CU.
//            W_hh bf16 B-frags in VGPRs; h f32 in regs; h bf16 in double-buffered LDS
//            (MFMA-A-fragment order + XOR swizzle). ONE raw s_barrier per step with
//            lgkmcnt-only drain -> global xg prefetch survives the barrier.

typedef __bf16 bf16x8 __attribute__((ext_vector_type(8)));
typedef float  f32x4  __attribute__((ext_vector_type(4)));
typedef int    int4v  __attribute__((ext_vector_type(4)));
typedef unsigned int uint4v __attribute__((ext_vector_type(4)));

#define NV   1000
#define EMB  64
#define HD   128
#define G3   384
#define SEQ  64
#define BB   16   // batch rows per block

__device__ __forceinline__ float sigm_f(float x) {
    return __builtin_amdgcn_rcpf(1.f + __builtin_amdgcn_exp2f(-1.44269504088896f * x));
}
__device__ __forceinline__ float tanh_f(float x) {
    return 1.f - 2.f * __builtin_amdgcn_rcpf(1.f + __builtin_amdgcn_exp2f(2.88539008177793f * x));
}
__device__ __forceinline__ float bfslot(uint4v w, int s) {   // s is unroll-constant
    const unsigned int word = w[s >> 1];
    const unsigned int bits = (s & 1) ? (word & 0xffff0000u) : (word << 16);
    return __builtin_bit_cast(float, bits);
}

__global__ void g_table_kernel(const float* __restrict__ embed,
                               const float* __restrict__ W_ih,
                               const float* __restrict__ b_ih,
                               const float* __restrict__ b_hh,
                               unsigned short* __restrict__ Gpk)
{
    __shared__ float emb[EMB];
    const int v = blockIdx.x;
    const int g = threadIdx.x;              // 0..383 = gate*128 + hid
    if (g < EMB) emb[g] = embed[v * EMB + g];
    __syncthreads();
    const float* wr = W_ih + g * EMB;
    float s = b_ih[g] + (g < 2 * HD ? b_hh[g] : 0.f);   // fold b_hh for r,z only
    #pragma unroll
    for (int e = 0; e < EMB; e += 4) {
        const float4 w4 = *(const float4*)(wr + e);
        s += w4.x * emb[e] + w4.y * emb[e + 1] + w4.z * emb[e + 2] + w4.w * emb[e + 3];
    }
    const int hid = g & 127, gate = g >> 7;
    const int cwi = hid >> 5, hti = (hid >> 4) & 1, c16i = hid & 15;
    Gpk[((v * 4 + cwi) * 16 + c16i) * 8 + (gate + 3 * hti)] =
        __builtin_bit_cast(unsigned short, (__bf16)s);
}

// ---- one GRU timestep. P = LDS read-buffer parity (compile-time), PFU/PFN = pf regs.
#define GRU_STEP(P, PFU, PFN, T)                                                   \
  {                                                                                \
    int4v tokn = {0, 0, 0, 0};                                                     \
    if ((T) < SEQ - 1) tokn = *(const int4v*)&xl[((T) + 1) * BB + quad * 4];       \
    f32x4 acc[3][2];                                                               \
    _Pragma("unroll") for (int g2 = 0; g2 < 3; ++g2) {                             \
      acc[g2][0] = z4; acc[g2][1] = z4;                                            \
    }                                                                              \
    _Pragma("unroll") for (int ks = 0; ks < 4; ++ks) {                             \
      const bf16x8 af = *(const bf16x8*)(hbase + (P) * 4096 + aoff[ks]);           \
      _Pragma("unroll") for (int gate = 0; gate < 3; ++gate)                       \
        _Pragma("unroll") for (int ht = 0; ht < 2; ++ht)                           \
          acc[gate][ht] = __builtin_amdgcn_mfma_f32_16x16x32_bf16(                 \
              af, wf[gate][ht][ks], acc[gate][ht], 0, 0, 0);                       \
    }                                                                              \
    if ((T) < SEQ - 1) {                                                           \
      _Pragma("unroll") for (int j = 0; j < 4; ++j)                                \
        PFN[j] = *(const uint4v*)(gbase + (unsigned)(tokn[j] * 1024 + goff));      \
    }                                                                              \
    _Pragma("unroll") for (int ht = 0; ht < 2; ++ht) {                             \
      const float bn_ = ht ? bn1 : bn0;                                            \
      _Pragma("unroll") for (int j = 0; j < 4; ++j) {                              \
        const float xr = bfslot(PFU[j], 3 * ht + 0);                               \
        const float xz = bfslot(PFU[j], 3 * ht + 1);                               \
        const float xn = bfslot(PFU[j], 3 * ht + 2);                               \
        const float r  = sigm_f(xr + acc[0][ht][j]);                               \
        const float zg = sigm_f(xz + acc[1][ht][j]);                               \
        const float n  = tanh_f(xn + r * (acc[2][ht][j] + bn_));                   \
        const float hn = zg * (hreg[ht][j] - n) + n;                               \
        hreg[ht][j] = hn;                                                          \
        *(unsigned short*)(hbase + (1 - (P)) * 4096 + woff[ht][j]) =               \
            __builtin_bit_cast(unsigned short, (__bf16)hn);                        \
      }                                                                            \
    }                                                                              \
    asm volatile("s_waitcnt lgkmcnt(0)" ::: "memory");                             \
    __builtin_amdgcn_s_barrier();                                                  \
    __builtin_amdgcn_sched_barrier(0);                                             \
  }

__global__ __launch_bounds__(256, 2) void gru_kernel(
    const int*   __restrict__ x,    const unsigned short* __restrict__ Gpk,
    const float* __restrict__ Whh,  const float* __restrict__ bhh,
    const float* __restrict__ Wout, const float* __restrict__ bout,
    float* __restrict__ out)
{
    __shared__ unsigned short hA[2 * BB * HD];   // 2 x 4KB, frag-permuted + XOR swizzle
    __shared__ int xl[SEQ * BB];                 // [t][row]

    const int tid  = threadIdx.x;
    const int lane = tid & 63;
    const int cw   = tid >> 6;      // wave id 0..3 = column team
    const int c16  = lane & 15;
    const int quad = lane >> 4;
    const int br0  = blockIdx.x * BB;

    // ---- stage tokens transposed: xl[t*BB + r] = x[(br0+r)*SEQ + t]
    #pragma unroll
    for (int i = 0; i < 4; ++i) {
        const int r = (tid >> 6) + i * 4;
        const int t = tid & 63;
        xl[t * BB + r] = x[(br0 + r) * SEQ + t];
    }
    // ---- zero hA buf0 (h0 = 0): 4096B = 1024 dwords
    #pragma unroll
    for (int i = 0; i < 4; ++i)
        ((unsigned int*)hA)[tid + i * 256] = 0u;

    // ---- W_hh B-fragments (weight-stationary)
    bf16x8 wf[3][2][4];
    #pragma unroll
    for (int gate = 0; gate < 3; ++gate)
    #pragma unroll
    for (int ht = 0; ht < 2; ++ht)
    #pragma unroll
    for (int ks = 0; ks < 4; ++ks) {
        const int col = gate * HD + cw * 32 + ht * 16 + c16;
        const float* p = Whh + col * HD + ks * 32 + quad * 4;
        const float4 a = *(const float4*)p;
        const float4 b = *(const float4*)(p + 16);
        bf16x8 f;
        f[0] = (__bf16)a.x; f[1] = (__bf16)a.y; f[2] = (__bf16)a.z; f[3] = (__bf16)a.w;
        f[4] = (__bf16)b.x; f[5] = (__bf16)b.y; f[6] = (__bf16)b.z; f[7] = (__bf16)b.w;
        wf[gate][ht][ks] = f;
    }

    const float bn0 = bhh[2 * HD + cw * 32 + c16];
    const float bn1 = bhh[2 * HD + cw * 32 + 16 + c16];

    // ---- hoisted per-lane-constant LDS offsets
    int aoff[4];
    #pragma unroll
    for (int ks = 0; ks < 4; ++ks)
        aoff[ks] = c16 * 256 + ((ks * 64 + quad * 16) ^ ((c16 & 7) << 4));
    int woff[2][4];
    #pragma unroll
    for (int ht = 0; ht < 2; ++ht)
    #pragma unroll
    for (int j = 0; j < 4; ++j) {
        const int hid  = cw * 32 + ht * 16 + c16;
        const int sidx = ((hid >> 5) << 5) | (((hid & 15) >> 2) << 3)
                       | (((hid >> 4) & 1) << 2) | (hid & 3);
        const int row  = quad * 4 + j;
        woff[ht][j] = row * 256 + ((sidx * 2) ^ ((row & 7) << 4));
    }

    char* hbase = (char*)hA;
    const char* gbase = (const char*)Gpk;
    const int goff = cw * 256 + c16 * 16;

    float hreg[2][4] = {{0.f, 0.f, 0.f, 0.f}, {0.f, 0.f, 0.f, 0.f}};
    const f32x4 z4 = {0.f, 0.f, 0.f, 0.f};

    __syncthreads();   // xl + hA zeros visible (one-time full drain is fine)

    // ---- preload xg for t=0
    uint4v pfA[4], pfB[4];
    {
        const int4v tok0 = *(const int4v*)&xl[0 * BB + quad * 4];
        #pragma unroll
        for (int j = 0; j < 4; ++j)
            pfA[j] = *(const uint4v*)(gbase + (unsigned)(tok0[j] * 1024 + goff));
    }

    for (int tt = 0; tt < SEQ; tt += 2) {
        GRU_STEP(0, pfA, pfB, tt);       // reads buf0, writes buf1
        GRU_STEP(1, pfB, pfA, tt + 1);   // reads buf1, writes buf0
    }
    // after t=63 (odd): h_final is in buf0; last barrier already executed.

    // ---- epilogue: out = h_final @ W_out^T + b_out
    bf16x8 wo[2][4];
    #pragma unroll
    for (int ht = 0; ht < 2; ++ht)
    #pragma unroll
    for (int ks = 0; ks < 4; ++ks) {
        const int col = cw * 32 + ht * 16 + c16;
        const float* p = Wout + col * HD + ks * 32 + quad * 4;
        const float4 a = *(const float4*)p;
        const float4 b = *(const float4*)(p + 16);
        bf16x8 f;
        f[0] = (__bf16)a.x; f[1] = (__bf16)a.y; f[2] = (__bf16)a.z; f[3] = (__bf16)a.w;
        f[4] = (__bf16)b.x; f[5] = (__bf16)b.y; f[6] = (__bf16)b.z; f[7] = (__bf16)b.w;
        wo[ht][ks] = f;
    }
    const float bo0 = bout[cw * 32 + c16];
    const float bo1 = bout[cw * 32 + 16 + c16];

    f32x4 oacc[2] = {z4, z4};
    #pragma unroll
    for (int ks = 0; ks < 4; ++ks) {
        const bf16x8 af = *(const bf16x8*)(hbase + aoff[ks]);   // buf0
        #pragma unroll
        for (int ht = 0; ht < 2; ++ht)
            oacc[ht] = __builtin_amdgcn_mfma_f32_16x16x32_bf16(af, wo[ht][ks], oacc[ht], 0, 0, 0);
    }
    #pragma unroll
    for (int ht = 0; ht < 2; ++ht) {
        const float bo_ = ht ? bo1 : bo0;
        #pragma unroll
        for (int j = 0; j < 4; ++j) {
            const int row = br0 + quad * 4 + j;
            out[row * HD + cw * 32 + ht * 16 + c16] = oacc[ht][j] + bo_;
        }
    }
}

extern "C" void kernel_launch(void* const* d_in, const int* in_sizes, int n_in,
                              void* d_out, int out_size, void* d_ws, size_t ws_size,
                              hipStream_t stream) {
    const int*   x     = (const int*)  d_in[0];
    const float* embed = (const float*)d_in[1];
    const float* W_ih  = (const float*)d_in[2];
    const float* W_hh  = (const float*)d_in[3];
    const float* b_ih  = (const float*)d_in[4];
    const float* b_hh  = (const float*)d_in[5];
    const float* W_out = (const float*)d_in[6];
    const float* b_out = (const float*)d_in[7];
    float* outp = (float*)d_out;
    unsigned short* Gpk = (unsigned short*)d_ws;   // 1000*4*16*8*2B = 1.024 MB

    const int Bsz = in_sizes[0] / SEQ;             // 8192

    g_table_kernel<<<NV, G3, 0, stream>>>(embed, W_ih, b_ih, b_hh, Gpk);
    gru_kernel<<<Bsz / BB, 256, 0, stream>>>(x, Gpk, W_hh, b_hh, W_out, b_out, outp);
}

// Round 6
// 103.113 us; speedup vs baseline: 1.1476x; 1.1476x over previous
//
#include <hip/hip_runtime.h>

// GRU encoder, MI355X — R5 (resubmit after infra failure; never measured).
// vs R2: pointwise VALU diet. Gate scales (-log2e for r,z; +2log2e for n) folded into
// the G table and W_hh/b_hh; xg' and bn' injected via MFMA C-init instead of adds.
// Cell: r=rcp(1+exp2(a0)); z=rcp(1+exp2(a1)); n=fma(-2,rcp(1+exp2(fma(r,a2,xn'))),1);
//       h=fma(z,h-n,n).  Geometry unchanged: 512 blk x 256 thr, BB=16, dbuf LDS h,
// one raw s_barrier/step with lgkmcnt-only drain.

typedef __bf16 bf16x8 __attribute__((ext_vector_type(8)));
typedef float  f32x4  __attribute__((ext_vector_type(4)));
typedef int    int4v  __attribute__((ext_vector_type(4)));
typedef unsigned int uint4v __attribute__((ext_vector_type(4)));

#define NV   1000
#define EMB  64
#define HD   128
#define G3   384
#define SEQ  64
#define BB   16   // batch rows per block

#define SC_RZ (-1.4426950408889634f)   // -log2(e): sigmoid(s)=rcp(1+exp2(-log2e*s))
#define SC_N  ( 2.8853900817779268f)   // +2log2(e): tanh(v)=1-2*rcp(1+exp2(2log2e*v))

__device__ __forceinline__ float bfslot(uint4v w, int s) {   // s is unroll-constant
    const unsigned int word = w[s >> 1];
    const unsigned int bits = (s & 1) ? (word & 0xffff0000u) : (word << 16);
    return __builtin_bit_cast(float, bits);
}

__global__ void g_table_kernel(const float* __restrict__ embed,
                               const float* __restrict__ W_ih,
                               const float* __restrict__ b_ih,
                               const float* __restrict__ b_hh,
                               unsigned short* __restrict__ Gpk)
{
    __shared__ float emb[EMB];
    const int v = blockIdx.x;
    const int g = threadIdx.x;              // 0..383 = gate*128 + hid
    if (g < EMB) emb[g] = embed[v * EMB + g];
    __syncthreads();
    const float* wr = W_ih + g * EMB;
    float s = b_ih[g] + (g < 2 * HD ? b_hh[g] : 0.f);   // fold b_hh for r,z only
    #pragma unroll
    for (int e = 0; e < EMB; e += 4) {
        const float4 w4 = *(const float4*)(wr + e);
        s += w4.x * emb[e] + w4.y * emb[e + 1] + w4.z * emb[e + 2] + w4.w * emb[e + 3];
    }
    const int hid = g & 127, gate = g >> 7;
    s *= (gate < 2) ? SC_RZ : SC_N;                      // pre-scale for exp2-form gates
    const int cwi = hid >> 5, hti = (hid >> 4) & 1, c16i = hid & 15;
    Gpk[((v * 4 + cwi) * 16 + c16i) * 8 + (gate + 3 * hti)] =
        __builtin_bit_cast(unsigned short, (__bf16)s);
}

// ---- one GRU timestep. P = LDS read-buffer parity (compile-time), PFU/PFN = pf regs.
#define GRU_STEP(P, PFU, PFN, T)                                                   \
  {                                                                                \
    int4v tokn = {0, 0, 0, 0};                                                     \
    if ((T) < SEQ - 1) tokn = *(const int4v*)&xl[((T) + 1) * BB + quad * 4];       \
    f32x4 acc[3][2];                                                               \
    float xn_[2][4];                                                               \
    _Pragma("unroll") for (int ht = 0; ht < 2; ++ht)                               \
      _Pragma("unroll") for (int j = 0; j < 4; ++j) {                              \
        acc[0][ht][j] = bfslot(PFU[j], 3 * ht + 0);   /* xr' (scaled) */           \
        acc[1][ht][j] = bfslot(PFU[j], 3 * ht + 1);   /* xz' (scaled) */           \
        acc[2][ht][j] = ht ? bn1 : bn0;               /* bn' (scaled) */           \
        xn_[ht][j]    = bfslot(PFU[j], 3 * ht + 2);   /* xn' (scaled) */           \
      }                                                                            \
    _Pragma("unroll") for (int ks = 0; ks < 4; ++ks) {                             \
      const bf16x8 af = *(const bf16x8*)(hbase + (P) * 4096 + aoff[ks]);           \
      _Pragma("unroll") for (int gate = 0; gate < 3; ++gate)                       \
        _Pragma("unroll") for (int ht = 0; ht < 2; ++ht)                           \
          acc[gate][ht] = __builtin_amdgcn_mfma_f32_16x16x32_bf16(                 \
              af, wf[gate][ht][ks], acc[gate][ht], 0, 0, 0);                       \
    }                                                                              \
    if ((T) < SEQ - 1) {                                                           \
      _Pragma("unroll") for (int j = 0; j < 4; ++j)                                \
        PFN[j] = *(const uint4v*)(gbase + (unsigned)(tokn[j] * 1024 + goff));      \
    }                                                                              \
    _Pragma("unroll") for (int ht = 0; ht < 2; ++ht) {                             \
      _Pragma("unroll") for (int j = 0; j < 4; ++j) {                              \
        const float r  = __builtin_amdgcn_rcpf(                                    \
            1.f + __builtin_amdgcn_exp2f(acc[0][ht][j]));                          \
        const float zg = __builtin_amdgcn_rcpf(                                    \
            1.f + __builtin_amdgcn_exp2f(acc[1][ht][j]));                          \
        const float v  = __builtin_fmaf(r, acc[2][ht][j], xn_[ht][j]);             \
        const float n  = __builtin_fmaf(-2.f,                                      \
            __builtin_amdgcn_rcpf(1.f + __builtin_amdgcn_exp2f(v)), 1.f);          \
        const float hn = __builtin_fmaf(zg, hreg[ht][j] - n, n);                   \
        hreg[ht][j] = hn;                                                          \
        *(unsigned short*)(hbase + (1 - (P)) * 4096 + woff[ht][j]) =               \
            __builtin_bit_cast(unsigned short, (__bf16)hn);                        \
      }                                                                            \
    }                                                                              \
    asm volatile("s_waitcnt lgkmcnt(0)" ::: "memory");                             \
    __builtin_amdgcn_s_barrier();                                                  \
    __builtin_amdgcn_sched_barrier(0);                                             \
  }

__global__ __launch_bounds__(256, 2) void gru_kernel(
    const int*   __restrict__ x,    const unsigned short* __restrict__ Gpk,
    const float* __restrict__ Whh,  const float* __restrict__ bhh,
    const float* __restrict__ Wout, const float* __restrict__ bout,
    float* __restrict__ out)
{
    __shared__ unsigned short hA[2 * BB * HD];   // 2 x 4KB, frag-permuted + XOR swizzle
    __shared__ int xl[SEQ * BB];                 // [t][row]

    const int tid  = threadIdx.x;
    const int lane = tid & 63;
    const int cw   = tid >> 6;      // wave id 0..3 = column team
    const int c16  = lane & 15;
    const int quad = lane >> 4;
    const int br0  = blockIdx.x * BB;

    // ---- stage tokens transposed: xl[t*BB + r] = x[(br0+r)*SEQ + t]
    #pragma unroll
    for (int i = 0; i < 4; ++i) {
        const int r = (tid >> 6) + i * 4;
        const int t = tid & 63;
        xl[t * BB + r] = x[(br0 + r) * SEQ + t];
    }
    // ---- zero hA buf0 (h0 = 0): 4096B = 1024 dwords
    #pragma unroll
    for (int i = 0; i < 4; ++i)
        ((unsigned int*)hA)[tid + i * 256] = 0u;

    // ---- W_hh B-fragments (weight-stationary, gate-scaled)
    bf16x8 wf[3][2][4];
    #pragma unroll
    for (int gate = 0; gate < 3; ++gate)
    #pragma unroll
    for (int ht = 0; ht < 2; ++ht)
    #pragma unroll
    for (int ks = 0; ks < 4; ++ks) {
        const float sc = (gate < 2) ? SC_RZ : SC_N;
        const int col = gate * HD + cw * 32 + ht * 16 + c16;
        const float* p = Whh + col * HD + ks * 32 + quad * 4;
        const float4 a = *(const float4*)p;
        const float4 b = *(const float4*)(p + 16);
        bf16x8 f;
        f[0] = (__bf16)(sc * a.x); f[1] = (__bf16)(sc * a.y);
        f[2] = (__bf16)(sc * a.z); f[3] = (__bf16)(sc * a.w);
        f[4] = (__bf16)(sc * b.x); f[5] = (__bf16)(sc * b.y);
        f[6] = (__bf16)(sc * b.z); f[7] = (__bf16)(sc * b.w);
        wf[gate][ht][ks] = f;
    }

    const float bn0 = SC_N * bhh[2 * HD + cw * 32 + c16];        // scaled n-bias
    const float bn1 = SC_N * bhh[2 * HD + cw * 32 + 16 + c16];

    // ---- hoisted per-lane-constant LDS offsets
    int aoff[4];
    #pragma unroll
    for (int ks = 0; ks < 4; ++ks)
        aoff[ks] = c16 * 256 + ((ks * 64 + quad * 16) ^ ((c16 & 7) << 4));
    int woff[2][4];
    #pragma unroll
    for (int ht = 0; ht < 2; ++ht)
    #pragma unroll
    for (int j = 0; j < 4; ++j) {
        const int hid  = cw * 32 + ht * 16 + c16;
        const int sidx = ((hid >> 5) << 5) | (((hid & 15) >> 2) << 3)
                       | (((hid >> 4) & 1) << 2) | (hid & 3);
        const int row  = quad * 4 + j;
        woff[ht][j] = row * 256 + ((sidx * 2) ^ ((row & 7) << 4));
    }

    char* hbase = (char*)hA;
    const char* gbase = (const char*)Gpk;
    const int goff = cw * 256 + c16 * 16;

    float hreg[2][4] = {{0.f, 0.f, 0.f, 0.f}, {0.f, 0.f, 0.f, 0.f}};
    const f32x4 z4 = {0.f, 0.f, 0.f, 0.f};

    __syncthreads();   // xl + hA zeros visible (one-time full drain is fine)

    // ---- preload xg for t=0
    uint4v pfA[4], pfB[4];
    {
        const int4v tok0 = *(const int4v*)&xl[0 * BB + quad * 4];
        #pragma unroll
        for (int j = 0; j < 4; ++j)
            pfA[j] = *(const uint4v*)(gbase + (unsigned)(tok0[j] * 1024 + goff));
    }

    for (int tt = 0; tt < SEQ; tt += 2) {
        GRU_STEP(0, pfA, pfB, tt);       // reads buf0, writes buf1
        GRU_STEP(1, pfB, pfA, tt + 1);   // reads buf1, writes buf0
    }
    // after t=63 (odd): h_final is in buf0; last barrier already executed.

    // ---- epilogue: out = h_final @ W_out^T + b_out
    bf16x8 wo[2][4];
    #pragma unroll
    for (int ht = 0; ht < 2; ++ht)
    #pragma unroll
    for (int ks = 0; ks < 4; ++ks) {
        const int col = cw * 32 + ht * 16 + c16;
        const float* p = Wout + col * HD + ks * 32 + quad * 4;
        const float4 a = *(const float4*)p;
        const float4 b = *(const float4*)(p + 16);
        bf16x8 f;
        f[0] = (__bf16)a.x; f[1] = (__bf16)a.y; f[2] = (__bf16)a.z; f[3] = (__bf16)a.w;
        f[4] = (__bf16)b.x; f[5] = (__bf16)b.y; f[6] = (__bf16)b.z; f[7] = (__bf16)b.w;
        wo[ht][ks] = f;
    }
    const float bo0 = bout[cw * 32 + c16];
    const float bo1 = bout[cw * 32 + 16 + c16];

    f32x4 oacc[2] = {z4, z4};
    #pragma unroll
    for (int ks = 0; ks < 4; ++ks) {
        const bf16x8 af = *(const bf16x8*)(hbase + aoff[ks]);   // buf0
        #pragma unroll
        for (int ht = 0; ht < 2; ++ht)
            oacc[ht] = __builtin_amdgcn_mfma_f32_16x16x32_bf16(af, wo[ht][ks], oacc[ht], 0, 0, 0);
    }
    #pragma unroll
    for (int ht = 0; ht < 2; ++ht) {
        const float bo_ = ht ? bo1 : bo0;
        #pragma unroll
        for (int j = 0; j < 4; ++j) {
            const int row = br0 + quad * 4 + j;
            out[row * HD + cw * 32 + ht * 16 + c16] = oacc[ht][j] + bo_;
        }
    }
}

extern "C" void kernel_launch(void* const* d_in, const int* in_sizes, int n_in,
                              void* d_out, int out_size, void* d_ws, size_t ws_size,
                              hipStream_t stream) {
    const int*   x     = (const int*)  d_in[0];
    const float* embed = (const float*)d_in[1];
    const float* W_ih  = (const float*)d_in[2];
    const float* W_hh  = (const float*)d_in[3];
    const float* b_ih  = (const float*)d_in[4];
    const float* b_hh  = (const float*)d_in[5];
    const float* W_out = (const float*)d_in[6];
    const float* b_out = (const float*)d_in[7];
    float* outp = (float*)d_out;
    unsigned short* Gpk = (unsigned short*)d_ws;   // 1000*4*16*8*2B = 1.024 MB

    const int Bsz = in_sizes[0] / SEQ;             // 8192

    g_table_kernel<<<NV, G3, 0, stream>>>(embed, W_ih, b_ih, b_hh, Gpk);
    gru_kernel<<<Bsz / BB, 256, 0, stream>>>(x, Gpk, W_hh, b_hh, W_out, b_out, outp);
}